// Round 1
// baseline (206.697 us; speedup 1.0000x reference)
//
#include <hip/hip_runtime.h>
#include <math.h>

#define S 8192
#define D 64
#define N 2048
#define O 8

// One block per row. Blocks [0,N) -> w0 (width D), [N,2N) -> w1 (width N),
// [2N,3N) -> w2 (width N), [3N,3N+O) -> w_out (width N).
// ws layout (floats): lse0[0..N) lse1[N..2N) lse2[2N..3N) lseo[3N..3N+O)
__global__ __launch_bounds__(256) void lse_all_kernel(
    const float* __restrict__ w0, const float* __restrict__ w1,
    const float* __restrict__ w2, const float* __restrict__ w_out,
    float* __restrict__ ws) {
    int b = blockIdx.x;
    const float* w;
    int W, row;
    float* out;
    if (b < N)          { w = w0;    W = D; row = b;         out = ws;         }
    else if (b < 2 * N) { w = w1;    W = N; row = b - N;     out = ws + N;     }
    else if (b < 3 * N) { w = w2;    W = N; row = b - 2 * N; out = ws + 2 * N; }
    else                { w = w_out; W = N; row = b - 3 * N; out = ws + 3 * N; }

    const float* rp = w + (size_t)row * W;

    // local max
    float m = -INFINITY;
    for (int i = threadIdx.x; i < W; i += blockDim.x)
        m = fmaxf(m, rp[i]);

    __shared__ float smax[4];
    __shared__ float ssum[4];
    int wave = threadIdx.x >> 6;
    int lane = threadIdx.x & 63;

    // wave-64 max reduce
    for (int off = 32; off >= 1; off >>= 1)
        m = fmaxf(m, __shfl_down(m, off, 64));
    if (lane == 0) smax[wave] = m;
    __syncthreads();
    if (threadIdx.x == 0) {
        float mm = fmaxf(fmaxf(smax[0], smax[1]), fmaxf(smax[2], smax[3]));
        smax[0] = mm;
    }
    __syncthreads();
    m = smax[0];

    // local sum of exp(w - max)
    float sum = 0.0f;
    for (int i = threadIdx.x; i < W; i += blockDim.x)
        sum += expf(rp[i] - m);
    for (int off = 32; off >= 1; off >>= 1)
        sum += __shfl_down(sum, off, 64);
    if (lane == 0) ssum[wave] = sum;
    __syncthreads();
    if (threadIdx.x == 0) {
        float ss = ssum[0] + ssum[1] + ssum[2] + ssum[3];
        out[row] = m + logf(ss);
    }
}

// One thread per (s, o). Walk the sampled path, accumulate log-prob, write
// out[0][s][o] = sin^3(x[s,cin]) and out[1][s][o] = exp(logp).
__global__ __launch_bounds__(256) void path_gather_kernel(
    const float* __restrict__ x,
    const float* __restrict__ w0, const float* __restrict__ w1,
    const float* __restrict__ w2, const float* __restrict__ w_out,
    const int* __restrict__ c0, const int* __restrict__ c1,
    const int* __restrict__ c2, const int* __restrict__ keys_out,
    const float* __restrict__ ws, float* __restrict__ out) {
    int t = blockIdx.x * blockDim.x + threadIdx.x;
    if (t >= S * O) return;
    int s = t >> 3;   // O == 8
    int o = t & 7;

    const float* lse0 = ws;
    const float* lse1 = ws + N;
    const float* lse2 = ws + 2 * N;
    const float* lseo = ws + 3 * N;

    int r2 = keys_out[t];                                 // [0, N)
    float logp = w_out[o * N + r2] - lseo[o];

    int r1 = c2[(size_t)s * N + r2];                      // [0, N)
    logp += w2[(size_t)r2 * N + r1] - lse2[r2];

    int r0 = c1[(size_t)s * N + r1];                      // [0, N)
    logp += w1[(size_t)r1 * N + r0] - lse1[r1];

    int cin = c0[(size_t)s * N + r0];                     // [0, D)
    logp += w0[r0 * D + cin] - lse0[r0];

    float y = sinf(sinf(sinf(x[s * D + cin])));

    out[t] = y;                 // output 0: y          [S*O]
    out[S * O + t] = expf(logp); // output 1: probas    [S*O]
}

extern "C" void kernel_launch(void* const* d_in, const int* in_sizes, int n_in,
                              void* d_out, int out_size, void* d_ws, size_t ws_size,
                              hipStream_t stream) {
    const float* x      = (const float*)d_in[0];
    const float* w0     = (const float*)d_in[1];
    const float* w1     = (const float*)d_in[2];
    const float* w2     = (const float*)d_in[3];
    const float* w_out  = (const float*)d_in[4];
    const int*   c0     = (const int*)d_in[5];
    const int*   c1     = (const int*)d_in[6];
    const int*   c2     = (const int*)d_in[7];
    const int*   keys_o = (const int*)d_in[8];
    float* out = (float*)d_out;
    float* ws  = (float*)d_ws;   // 3N + O floats of lse scratch

    // Pass 1: per-row logsumexp for all four weight matrices (one launch).
    lse_all_kernel<<<3 * N + O, 256, 0, stream>>>(w0, w1, w2, w_out, ws);

    // Pass 2: path walk + gather, one thread per (s, o).
    path_gather_kernel<<<(S * O) / 256, 256, 0, stream>>>(
        x, w0, w1, w2, w_out, c0, c1, c2, keys_o, ws, out);
}

// Round 2
// 195.643 us; speedup vs baseline: 1.0565x; 1.0565x over previous
//
#include <hip/hip_runtime.h>
#include <math.h>
#include <float.h>

#define S 8192
#define D 64
#define N 2048
#define O 8

// One block per row, single-pass online logsumexp with float4 loads.
// Blocks [0,N) -> w0 (width D), [N,2N) -> w1, [2N,3N) -> w2, [3N,3N+O) -> w_out.
// ws layout (floats): lse0[0..N) lse1[N..2N) lse2[2N..3N) lseo[3N..3N+O)
__global__ __launch_bounds__(256) void lse_all_kernel(
    const float* __restrict__ w0, const float* __restrict__ w1,
    const float* __restrict__ w2, const float* __restrict__ w_out,
    float* __restrict__ ws) {
    int b = blockIdx.x;
    const float* w;
    int W, row;
    float* out;
    if (b < N)          { w = w0;    W = D; row = b;         out = ws;         }
    else if (b < 2 * N) { w = w1;    W = N; row = b - N;     out = ws + N;     }
    else if (b < 3 * N) { w = w2;    W = N; row = b - 2 * N; out = ws + 2 * N; }
    else                { w = w_out; W = N; row = b - 3 * N; out = ws + 3 * N; }

    const float4* rp4 = (const float4*)(w + (size_t)row * W);
    int n4 = W >> 2;

    // online (m, sum) state; -FLT_MAX (not -inf) so merges of empty states
    // give exp(0)=1 * 0 = 0 instead of 0*NaN.
    float m = -FLT_MAX;
    float sum = 0.0f;
    for (int i = threadIdx.x; i < n4; i += 256) {
        float4 v = rp4[i];
        float mv = fmaxf(fmaxf(v.x, v.y), fmaxf(v.z, v.w));
        float nm = fmaxf(m, mv);
        sum = sum * __expf(m - nm)
            + __expf(v.x - nm) + __expf(v.y - nm)
            + __expf(v.z - nm) + __expf(v.w - nm);
        m = nm;
    }

    // wave-64 online merge
    for (int off = 32; off >= 1; off >>= 1) {
        float mo = __shfl_down(m, off, 64);
        float so = __shfl_down(sum, off, 64);
        float nm = fmaxf(m, mo);
        sum = sum * __expf(m - nm) + so * __expf(mo - nm);
        m = nm;
    }

    __shared__ float sm[4], ss[4];
    int wave = threadIdx.x >> 6;
    int lane = threadIdx.x & 63;
    if (lane == 0) { sm[wave] = m; ss[wave] = sum; }
    __syncthreads();
    if (threadIdx.x == 0) {
        float M = sm[0], Sm = ss[0];
        for (int i = 1; i < 4; ++i) {
            float nm = fmaxf(M, sm[i]);
            Sm = Sm * __expf(M - nm) + ss[i] * __expf(sm[i] - nm);
            M = nm;
        }
        out[row] = M + __logf(Sm);
    }
}

// One thread per (s, o). Walk the sampled path, accumulate log-prob, write
// out[0][s][o] = sin^3(x[s,cin]) and out[1][s][o] = exp(logp).
__global__ __launch_bounds__(256) void path_gather_kernel(
    const float* __restrict__ x,
    const float* __restrict__ w0, const float* __restrict__ w1,
    const float* __restrict__ w2, const float* __restrict__ w_out,
    const int* __restrict__ c0, const int* __restrict__ c1,
    const int* __restrict__ c2, const int* __restrict__ keys_out,
    const float* __restrict__ ws, float* __restrict__ out) {
    int t = blockIdx.x * blockDim.x + threadIdx.x;
    int s = t >> 3;   // O == 8
    int o = t & 7;

    const float* lse0 = ws;
    const float* lse1 = ws + N;
    const float* lse2 = ws + 2 * N;
    const float* lseo = ws + 3 * N;

    int r2 = keys_out[t];                                 // [0, N)
    float logp = w_out[o * N + r2] - lseo[o];

    int r1 = c2[(size_t)s * N + r2];                      // [0, N)
    logp += w2[(size_t)r2 * N + r1] - lse2[r2];

    int r0 = c1[(size_t)s * N + r1];                      // [0, N)
    logp += w1[(size_t)r1 * N + r0] - lse1[r1];

    int cin = c0[(size_t)s * N + r0];                     // [0, D)
    logp += w0[r0 * D + cin] - lse0[r0];

    float y = sinf(sinf(sinf(x[s * D + cin])));

    out[t] = y;                   // output 0: y       [S*O]
    out[S * O + t] = __expf(logp); // output 1: probas [S*O]
}

extern "C" void kernel_launch(void* const* d_in, const int* in_sizes, int n_in,
                              void* d_out, int out_size, void* d_ws, size_t ws_size,
                              hipStream_t stream) {
    const float* x      = (const float*)d_in[0];
    const float* w0     = (const float*)d_in[1];
    const float* w1     = (const float*)d_in[2];
    const float* w2     = (const float*)d_in[3];
    const float* w_out  = (const float*)d_in[4];
    const int*   c0     = (const int*)d_in[5];
    const int*   c1     = (const int*)d_in[6];
    const int*   c2     = (const int*)d_in[7];
    const int*   keys_o = (const int*)d_in[8];
    float* out = (float*)d_out;
    float* ws  = (float*)d_ws;   // 3N + O floats of lse scratch

    // Pass 1: per-row logsumexp for all four weight matrices (one launch).
    lse_all_kernel<<<3 * N + O, 256, 0, stream>>>(w0, w1, w2, w_out, ws);

    // Pass 2: path walk + gather, one thread per (s, o).
    path_gather_kernel<<<(S * O) / 256, 256, 0, stream>>>(
        x, w0, w1, w2, w_out, c0, c1, c2, keys_o, ws, out);
}